// Round 10
// baseline (102.155 us; speedup 1.0000x reference)
//
#include <hip/hip_runtime.h>
#include <hip/hip_bf16.h>

// B=2048, NF=64, FD=32, S=32, D=32, OD=32
typedef __attribute__((ext_vector_type(4)))  _Float16 h4;
typedef __attribute__((ext_vector_type(8)))  _Float16 h8;
typedef __attribute__((ext_vector_type(4)))  float f32x4;
typedef __attribute__((ext_vector_type(16))) float f32x16;

// s-decode: sp = bid&31 -> s = ((sp&7)<<2)|(sp>>3)  => XCD(bid%8) = s>>2
__device__ __forceinline__ int sdecode(int sp) { return ((sp & 7) << 2) | (sp >> 3); }

// ---------------- conv: Rb[s][g][n][a] f16 ; Opp[s][c8][o][kk] ----
__global__ __launch_bounds__(64) void conv_kernel(
    const float* __restrict__ Rg, const float* __restrict__ Og,
    _Float16* __restrict__ Rb, char* __restrict__ Opp)
{
    __shared__ float tile[32][33];
    const int bid = blockIdx.x;
    const int s = sdecode(bid & 31), q = (bid >> 5) & 31, which = bid >> 10;
    const int t = threadIdx.x, tl = t & 31, th = t >> 5;

    if (which == 0) {
        #pragma unroll
        for (int j = 0; j < 16; ++j) {
            int ar = 2*j + th;
            tile[tl][ar] = Rg[(((size_t)s*32 + q)*32 + ar)*32 + tl];
        }
        __syncthreads();
        _Float16* dst = Rb + ((size_t)s*32 + q)*1024;
        #pragma unroll
        for (int it = 0; it < 4; ++it) {
            int nr = it*8 + (t >> 3), a0 = (t & 7)*4;
            h4 w;
            #pragma unroll
            for (int k = 0; k < 4; ++k) w[k] = (_Float16)tile[nr][a0 + k];
            *(h4*)(dst + nr*32 + a0) = w;
        }
    } else {
        #pragma unroll
        for (int j = 0; j < 16; ++j) {
            int nr = 2*j + th;
            tile[tl][nr] = Og[(((size_t)s*32 + q)*32 + nr)*32 + tl];
        }
        __syncthreads();
        char* dst = Opp + (size_t)s*65536 + q*2048;
        int o = t & 31, cq = t >> 5;
        #pragma unroll
        for (int it = 0; it < 2; ++it) {
            int c = it*2 + cq;
            h8 w;
            #pragma unroll
            for (int k = 0; k < 8; ++k) w[k] = (_Float16)tile[o][c*8 + k];
            *(h8*)(dst + c*512 + o*16) = w;
        }
    }
}

// ---------------- tmake: Tp[s][ks=f*2+gt][o][kk] ----
__global__ __launch_bounds__(256, 2) void tmake_kernel(
    const float* __restrict__ Lg, const _Float16* __restrict__ Rb,
    const char* __restrict__ Opp, char* __restrict__ Tp)
{
    __shared__ __align__(16) char Wl[65536];
    const int bid = blockIdx.x;
    const int s = sdecode(bid & 31), f = bid >> 5;
    const int t = threadIdx.x, wid = t >> 6, l = t & 63;
    const int llo = l & 15, lhi = l >> 4;

    const float* Lsf = Lg + ((size_t)s*32 + f)*1024;
    h8 bfr[2];
    #pragma unroll
    for (int mt = 0; mt < 2; ++mt)
        #pragma unroll
        for (int j = 0; j < 8; ++j)
            bfr[mt][j] = (_Float16)Lsf[(8*lhi + j)*32 + mt*16 + llo];

    const _Float16* Rbs = Rb + (size_t)s*32768;

    #pragma unroll 4
    for (int nt = 0; nt < 16; ++nt) {
        int gnb = (wid*16 + nt)*16;
        h8 af = *(const h8*)(Rbs + (gnb + llo)*32 + 8*lhi);
        int g = gnb >> 5;
        int nbase = (gnb & 31) + 4*lhi;
        #pragma unroll
        for (int mt = 0; mt < 2; ++mt) {
            f32x4 d = __builtin_amdgcn_mfma_f32_16x16x32_f16(af, bfr[mt], (f32x4)(0.f), 0, 0, 0);
            int m = mt*16 + llo;
            h4 w;
            #pragma unroll
            for (int r = 0; r < 4; ++r) w[r] = (_Float16)d[r];
            int byte = (g*2048 + m*64 + nbase*2) ^ ((((g & 7) ^ (m & 7))) << 4);
            *(h4*)(Wl + byte) = w;
        }
    }
    __syncthreads();

    const int ot = wid & 1, kq = wid >> 1;
    const int orow = ot*16 + llo;
    const char* Opps = Opp + (size_t)s*65536;
    f32x4 acc0 = (f32x4)(0.f), acc1 = (f32x4)(0.f);
    #pragma unroll 4
    for (int ksl = 0; ksl < 16; ++ksl) {
        int ks = kq*16 + ksl;
        h8 bf = *(const h8*)(Opps + (ks*4 + lhi)*512 + orow*16);
        {
            int grow = llo;
            int byte = (grow*2048 + ks*64 + lhi*16) ^ ((((grow & 7) ^ (ks & 7))) << 4);
            h8 af = *(const h8*)(Wl + byte);
            acc0 = __builtin_amdgcn_mfma_f32_16x16x32_f16(af, bf, acc0, 0, 0, 0);
        }
        {
            int grow = 16 + llo;
            int byte = (grow*2048 + ks*64 + lhi*16) ^ ((((grow & 7) ^ (ks & 7))) << 4);
            h8 af = *(const h8*)(Wl + byte);
            acc1 = __builtin_amdgcn_mfma_f32_16x16x32_f16(af, bf, acc1, 0, 0, 0);
        }
    }
    __syncthreads();
    if (kq == 1) {
        *(f32x4*)(Wl + ((ot*2 + 0)*64 + l)*16) = acc0;
        *(f32x4*)(Wl + ((ot*2 + 1)*64 + l)*16) = acc1;
    }
    __syncthreads();
    if (kq == 0) {
        acc0 += *(const f32x4*)(Wl + ((ot*2 + 0)*64 + l)*16);
        acc1 += *(const f32x4*)(Wl + ((ot*2 + 1)*64 + l)*16);
        char* Tps = Tp + (size_t)s*65536;
        h4 w0, w1;
        #pragma unroll
        for (int r = 0; r < 4; ++r) { w0[r] = (_Float16)acc0[r]; w1[r] = (_Float16)acc1[r]; }
        *(h4*)(Tps + (f*2 + 0)*1024 + orow*32 + lhi*8) = w0;
        *(h4*)(Tps + (f*2 + 1)*1024 + orow*32 + lhi*8) = w1;
    }
}

// ---------------- main v4 (x4 MEASUREMENT REPS): single-batch staging, acc ILP=4
__global__ __launch_bounds__(256, 2) void main_kernel(
    const float* __restrict__ x, const char* __restrict__ Tp,
    const float* __restrict__ bias, float* __restrict__ out)
{
    __shared__ __align__(16) char Tl[65536];

    const int bid = blockIdx.x;
    const int s = sdecode(bid & 31);
    const int b0 = (bid >> 5) * 128;
    const int t = threadIdx.x, wid = t >> 6, l = t & 63;
    const int lo5 = l & 31, hi = l >> 5;

    const char* Tps = Tp + (size_t)s*65536;
    const float* xrow = x + (size_t)(b0 + wid*32 + lo5)*2048 + s*64;
    const float* bias_s = bias + s*32;

    #pragma unroll 1
    for (int rep = 0; rep < 4; ++rep) {
        // ---- issue ALL loads up front (one latency round-trip) ----
        uint4 tv[16];
        #pragma unroll
        for (int i = 0; i < 16; ++i)
            tv[i] = *(const uint4*)(Tps + (i*256 + t)*16);

        float4 xlv[8];
        #pragma unroll
        for (int i = 0; i < 8; ++i) xlv[i] = *(const float4*)(xrow + i*4);
        const float* xrp = xrow + 32 + hi*8;
        float4 xr00 = *(const float4*)(xrp);
        float4 xr01 = *(const float4*)(xrp + 4);
        float4 xr10 = *(const float4*)(xrp + 16);
        float4 xr11 = *(const float4*)(xrp + 20);

        #pragma unroll
        for (int i = 0; i < 16; ++i)
            *(uint4*)(Tl + (i*256 + t)*16) = tv[i];

        // convert x to f16
        h4 xlh[8];
        #pragma unroll
        for (int i = 0; i < 8; ++i) {
            xlh[i][0] = (_Float16)xlv[i].x; xlh[i][1] = (_Float16)xlv[i].y;
            xlh[i][2] = (_Float16)xlv[i].z; xlh[i][3] = (_Float16)xlv[i].w;
        }
        h8 xr_a, xr_b;
        xr_a[0] = (_Float16)xr00.x; xr_a[1] = (_Float16)xr00.y;
        xr_a[2] = (_Float16)xr00.z; xr_a[3] = (_Float16)xr00.w;
        xr_a[4] = (_Float16)xr01.x; xr_a[5] = (_Float16)xr01.y;
        xr_a[6] = (_Float16)xr01.z; xr_a[7] = (_Float16)xr01.w;
        xr_b[0] = (_Float16)xr10.x; xr_b[1] = (_Float16)xr10.y;
        xr_b[2] = (_Float16)xr10.z; xr_b[3] = (_Float16)xr10.w;
        xr_b[4] = (_Float16)xr11.x; xr_b[5] = (_Float16)xr11.y;
        xr_b[6] = (_Float16)xr11.z; xr_b[7] = (_Float16)xr11.w;
        __syncthreads();

        // ---- K loop: 64 steps, acc ILP=4 ----
        f32x16 acc0 = (f32x16)(0.f), acc1 = (f32x16)(0.f);
        f32x16 acc2 = (f32x16)(0.f), acc3 = (f32x16)(0.f);
        #pragma unroll
        for (int ksl = 0; ksl < 64; ++ksl) {
            h8 bf = *(const h8*)(Tl + ksl*1024 + lo5*32 + hi*16);
            _Float16 xs = xlh[ksl >> 3][(ksl >> 1) & 3];
            if ((ksl & 3) == 0) {
                h8 z = xr_a * xs;
                acc0 = __builtin_amdgcn_mfma_f32_32x32x16_f16(z, bf, acc0, 0, 0, 0);
            } else if ((ksl & 3) == 1) {
                h8 z = xr_b * xs;
                acc1 = __builtin_amdgcn_mfma_f32_32x32x16_f16(z, bf, acc1, 0, 0, 0);
            } else if ((ksl & 3) == 2) {
                h8 z = xr_a * xs;
                acc2 = __builtin_amdgcn_mfma_f32_32x32x16_f16(z, bf, acc2, 0, 0, 0);
            } else {
                h8 z = xr_b * xs;
                acc3 = __builtin_amdgcn_mfma_f32_32x32x16_f16(z, bf, acc3, 0, 0, 0);
            }
        }
        f32x16 acc = (acc0 + acc2) + (acc1 + acc3);

        // ---- epilogue: stash in Tl, vectorized f32x4 stores ----
        __syncthreads();
        #pragma unroll
        for (int r = 0; r < 16; ++r) {
            int row = (r & 3) + 8*(r >> 2) + 4*hi;
            *(float*)(Tl + wid*4096 + row*128 + lo5*4) = acc[r];
        }
        __syncthreads();

        #pragma unroll
        for (int i = 0; i < 4; ++i) {
            int u = i*256 + t;
            int row = u >> 3, colq = u & 7;
            f32x4 v = *(const f32x4*)(Tl + u*16);
            f32x4 bv = *(const f32x4*)(bias_s + colq*4);
            *(f32x4*)(out + (size_t)(b0 + row)*1024 + s*32 + colq*4) = v + bv;
        }
        __syncthreads();   // rep isolation (Tl rewrite vs stores above)
    }
}

extern "C" void kernel_launch(void* const* d_in, const int* in_sizes, int n_in,
                              void* d_out, int out_size, void* d_ws, size_t ws_size,
                              hipStream_t stream) {
    const float* x    = (const float*)d_in[0];
    const float* L    = (const float*)d_in[1];
    const float* R    = (const float*)d_in[2];
    const float* O    = (const float*)d_in[3];
    const float* bias = (const float*)d_in[4];
    float* out = (float*)d_out;

    _Float16* Rb  = (_Float16*)d_ws;                 // 2 MB
    char*     Opp = (char*)d_ws + 2097152;           // 2 MB
    char*     Tp  = (char*)d_ws + 4194304;           // 2 MB

    conv_kernel<<<dim3(2048), 64, 0, stream>>>(R, O, Rb, Opp);
    tmake_kernel<<<dim3(1024), 256, 0, stream>>>(L, Rb, Opp, Tp);
    main_kernel<<<dim3(512), 256, 0, stream>>>(x, Tp, bias, out);
}

// Round 11
// 37.766 us; speedup vs baseline: 2.7049x; 2.7049x over previous
//
#include <hip/hip_runtime.h>
#include <hip/hip_bf16.h>

// B=2048, NF=64, FD=32, S=32, D=32, OD=32
typedef __attribute__((ext_vector_type(4)))  _Float16 h4;
typedef __attribute__((ext_vector_type(8)))  _Float16 h8;
typedef __attribute__((ext_vector_type(4)))  float f32x4;
typedef __attribute__((ext_vector_type(16))) float f32x16;

__device__ __forceinline__ int sdecode(int sp) { return ((sp & 7) << 2) | (sp >> 3); }

// ---------------- conv: Rb[s][g][n][a] f16 ; Opp[s][c8][o][kk] ----
__global__ __launch_bounds__(64) void conv_kernel(
    const float* __restrict__ Rg, const float* __restrict__ Og,
    _Float16* __restrict__ Rb, char* __restrict__ Opp)
{
    __shared__ float tile[32][33];
    const int bid = blockIdx.x;
    const int s = sdecode(bid & 31), q = (bid >> 5) & 31, which = bid >> 10;
    const int t = threadIdx.x, tl = t & 31, th = t >> 5;

    if (which == 0) {
        #pragma unroll
        for (int j = 0; j < 16; ++j) {
            int ar = 2*j + th;
            tile[tl][ar] = Rg[(((size_t)s*32 + q)*32 + ar)*32 + tl];
        }
        __syncthreads();
        _Float16* dst = Rb + ((size_t)s*32 + q)*1024;
        #pragma unroll
        for (int it = 0; it < 4; ++it) {
            int nr = it*8 + (t >> 3), a0 = (t & 7)*4;
            h4 w;
            #pragma unroll
            for (int k = 0; k < 4; ++k) w[k] = (_Float16)tile[nr][a0 + k];
            *(h4*)(dst + nr*32 + a0) = w;
        }
    } else {
        #pragma unroll
        for (int j = 0; j < 16; ++j) {
            int nr = 2*j + th;
            tile[tl][nr] = Og[(((size_t)s*32 + q)*32 + nr)*32 + tl];
        }
        __syncthreads();
        char* dst = Opp + (size_t)s*65536 + q*2048;
        int o = t & 31, cq = t >> 5;
        #pragma unroll
        for (int it = 0; it < 2; ++it) {
            int c = it*2 + cq;
            h8 w;
            #pragma unroll
            for (int k = 0; k < 8; ++k) w[k] = (_Float16)tile[o][c*8 + k];
            *(h8*)(dst + c*512 + o*16) = w;
        }
    }
}

// ---------------- tmake: Tp[s][ks=f*2+gt][o][kk] ----
__global__ __launch_bounds__(256, 2) void tmake_kernel(
    const float* __restrict__ Lg, const _Float16* __restrict__ Rb,
    const char* __restrict__ Opp, char* __restrict__ Tp)
{
    __shared__ __align__(16) char Wl[65536];
    const int bid = blockIdx.x;
    const int s = sdecode(bid & 31), f = bid >> 5;
    const int t = threadIdx.x, wid = t >> 6, l = t & 63;
    const int llo = l & 15, lhi = l >> 4;

    const float* Lsf = Lg + ((size_t)s*32 + f)*1024;
    h8 bfr[2];
    #pragma unroll
    for (int mt = 0; mt < 2; ++mt)
        #pragma unroll
        for (int j = 0; j < 8; ++j)
            bfr[mt][j] = (_Float16)Lsf[(8*lhi + j)*32 + mt*16 + llo];

    const _Float16* Rbs = Rb + (size_t)s*32768;

    #pragma unroll 4
    for (int nt = 0; nt < 16; ++nt) {
        int gnb = (wid*16 + nt)*16;
        h8 af = *(const h8*)(Rbs + (gnb + llo)*32 + 8*lhi);
        int g = gnb >> 5;
        int nbase = (gnb & 31) + 4*lhi;
        #pragma unroll
        for (int mt = 0; mt < 2; ++mt) {
            f32x4 d = __builtin_amdgcn_mfma_f32_16x16x32_f16(af, bfr[mt], (f32x4)(0.f), 0, 0, 0);
            int m = mt*16 + llo;
            h4 w;
            #pragma unroll
            for (int r = 0; r < 4; ++r) w[r] = (_Float16)d[r];
            int byte = (g*2048 + m*64 + nbase*2) ^ ((((g & 7) ^ (m & 7))) << 4);
            *(h4*)(Wl + byte) = w;
        }
    }
    __syncthreads();

    const int ot = wid & 1, kq = wid >> 1;
    const int orow = ot*16 + llo;
    const char* Opps = Opp + (size_t)s*65536;
    f32x4 acc0 = (f32x4)(0.f), acc1 = (f32x4)(0.f);
    #pragma unroll 4
    for (int ksl = 0; ksl < 16; ++ksl) {
        int ks = kq*16 + ksl;
        h8 bf = *(const h8*)(Opps + (ks*4 + lhi)*512 + orow*16);
        {
            int grow = llo;
            int byte = (grow*2048 + ks*64 + lhi*16) ^ ((((grow & 7) ^ (ks & 7))) << 4);
            h8 af = *(const h8*)(Wl + byte);
            acc0 = __builtin_amdgcn_mfma_f32_16x16x32_f16(af, bf, acc0, 0, 0, 0);
        }
        {
            int grow = 16 + llo;
            int byte = (grow*2048 + ks*64 + lhi*16) ^ ((((grow & 7) ^ (ks & 7))) << 4);
            h8 af = *(const h8*)(Wl + byte);
            acc1 = __builtin_amdgcn_mfma_f32_16x16x32_f16(af, bf, acc1, 0, 0, 0);
        }
    }
    __syncthreads();
    if (kq == 1) {
        *(f32x4*)(Wl + ((ot*2 + 0)*64 + l)*16) = acc0;
        *(f32x4*)(Wl + ((ot*2 + 1)*64 + l)*16) = acc1;
    }
    __syncthreads();
    if (kq == 0) {
        acc0 += *(const f32x4*)(Wl + ((ot*2 + 0)*64 + l)*16);
        acc1 += *(const f32x4*)(Wl + ((ot*2 + 1)*64 + l)*16);
        char* Tps = Tp + (size_t)s*65536;
        h4 w0, w1;
        #pragma unroll
        for (int r = 0; r < 4; ++r) { w0[r] = (_Float16)acc0[r]; w1[r] = (_Float16)acc1[r]; }
        *(h4*)(Tps + (f*2 + 0)*1024 + orow*32 + lhi*8) = w0;
        *(h4*)(Tps + (f*2 + 1)*1024 + orow*32 + lhi*8) = w1;
    }
}

// ---------------- main v5: 1-wave blocks, NO LDS, T direct from L2 via reg ring
// grid 2048 (s = bid&31, btile = bid>>5, 32 rows), 64 threads.
// Lane owns out-row b0+lo5; hi = k-fragment half. 8-deep global prefetch ring.
__global__ __launch_bounds__(64, 4) void main_kernel(
    const float* __restrict__ x, const char* __restrict__ Tp,
    const float* __restrict__ bias, float* __restrict__ out)
{
    const int bid = blockIdx.x;
    const int s = bid & 31;
    const int b0 = (bid >> 5) * 32;
    const int t = threadIdx.x;
    const int lo5 = t & 31, hi = t >> 5;

    const char* Tps = Tp + (size_t)s*65536;
    const char* Tbase = Tps + lo5*32 + hi*16;

    // per-lane x loads (row = b0 + lo5; hi lanes duplicate xl, split xr)
    const float* xrow = x + (size_t)(b0 + lo5)*2048 + s*64;
    float4 xlv[8];
    #pragma unroll
    for (int i = 0; i < 8; ++i) xlv[i] = *(const float4*)(xrow + i*4);
    const float* xrp = xrow + 32 + hi*8;
    float4 xr00 = *(const float4*)(xrp);
    float4 xr01 = *(const float4*)(xrp + 4);
    float4 xr10 = *(const float4*)(xrp + 16);
    float4 xr11 = *(const float4*)(xrp + 20);

    // prefetch ring: T[ks][o][kk], 1KB/wave coalesced per load
    h8 ring[8];
    #pragma unroll
    for (int i = 0; i < 8; ++i)
        ring[i] = *(const h8*)(Tbase + i*1024);

    // convert x to f16 (overlaps in-flight loads)
    h4 xlh[8];
    #pragma unroll
    for (int i = 0; i < 8; ++i) {
        xlh[i][0] = (_Float16)xlv[i].x; xlh[i][1] = (_Float16)xlv[i].y;
        xlh[i][2] = (_Float16)xlv[i].z; xlh[i][3] = (_Float16)xlv[i].w;
    }
    h8 xr_a, xr_b;
    xr_a[0] = (_Float16)xr00.x; xr_a[1] = (_Float16)xr00.y;
    xr_a[2] = (_Float16)xr00.z; xr_a[3] = (_Float16)xr00.w;
    xr_a[4] = (_Float16)xr01.x; xr_a[5] = (_Float16)xr01.y;
    xr_a[6] = (_Float16)xr01.z; xr_a[7] = (_Float16)xr01.w;
    xr_b[0] = (_Float16)xr10.x; xr_b[1] = (_Float16)xr10.y;
    xr_b[2] = (_Float16)xr10.z; xr_b[3] = (_Float16)xr10.w;
    xr_b[4] = (_Float16)xr11.x; xr_b[5] = (_Float16)xr11.y;
    xr_b[6] = (_Float16)xr11.z; xr_b[7] = (_Float16)xr11.w;

    // K loop: 64 steps, each 1 global h8 (prefetch +8) + 2 pk_mul + 1 MFMA
    f32x16 acc_e = (f32x16)(0.f), acc_o = (f32x16)(0.f);
    #pragma unroll
    for (int ksl = 0; ksl < 64; ++ksl) {
        h8 bf = ring[ksl & 7];
        if (ksl < 56)
            ring[ksl & 7] = *(const h8*)(Tbase + (ksl + 8)*1024);
        _Float16 xs = xlh[ksl >> 3][(ksl >> 1) & 3];
        if (ksl & 1) {
            h8 z = xr_b * xs;
            acc_o = __builtin_amdgcn_mfma_f32_32x32x16_f16(z, bf, acc_o, 0, 0, 0);
        } else {
            h8 z = xr_a * xs;
            acc_e = __builtin_amdgcn_mfma_f32_32x32x16_f16(z, bf, acc_e, 0, 0, 0);
        }
    }
    f32x16 acc = acc_e + acc_o;

    // epilogue: direct stores — 32 lanes x 4B = full 128B line per half-wave
    const float bv = bias[s*32 + lo5];
    #pragma unroll
    for (int r = 0; r < 16; ++r) {
        int row = (r & 3) + 8*(r >> 2) + 4*hi;        // 32x32 C/D row map
        out[(size_t)(b0 + row)*1024 + s*32 + lo5] = acc[r] + bv;
    }
}

extern "C" void kernel_launch(void* const* d_in, const int* in_sizes, int n_in,
                              void* d_out, int out_size, void* d_ws, size_t ws_size,
                              hipStream_t stream) {
    const float* x    = (const float*)d_in[0];
    const float* L    = (const float*)d_in[1];
    const float* R    = (const float*)d_in[2];
    const float* O    = (const float*)d_in[3];
    const float* bias = (const float*)d_in[4];
    float* out = (float*)d_out;

    _Float16* Rb  = (_Float16*)d_ws;                 // 2 MB
    char*     Opp = (char*)d_ws + 2097152;           // 2 MB
    char*     Tp  = (char*)d_ws + 4194304;           // 2 MB

    conv_kernel<<<dim3(2048), 64, 0, stream>>>(R, O, Rb, Opp);
    tmake_kernel<<<dim3(1024), 256, 0, stream>>>(L, Rb, Opp, Tp);
    main_kernel<<<dim3(2048), 64, 0, stream>>>(x, Tp, bias, out);
}

// Round 12
// 30.625 us; speedup vs baseline: 3.3356x; 1.2332x over previous
//
#include <hip/hip_runtime.h>
#include <hip/hip_bf16.h>

// B=2048, NF=64, FD=32, S=32, D=32, OD=32
typedef __attribute__((ext_vector_type(4)))  _Float16 h4;
typedef __attribute__((ext_vector_type(8)))  _Float16 h8;
typedef __attribute__((ext_vector_type(4)))  float f32x4;
typedef __attribute__((ext_vector_type(16))) float f32x16;
typedef __attribute__((ext_vector_type(4)))  unsigned int u32x4;

__device__ __forceinline__ int sdecode(int sp) { return ((sp & 7) << 2) | (sp >> 3); }

// ---------------- conv: Rb[s][g][n][a] f16 ; Opp[s][c8][o][kk] ----
__global__ __launch_bounds__(64) void conv_kernel(
    const float* __restrict__ Rg, const float* __restrict__ Og,
    _Float16* __restrict__ Rb, char* __restrict__ Opp)
{
    __shared__ float tile[32][33];
    const int bid = blockIdx.x;
    const int s = sdecode(bid & 31), q = (bid >> 5) & 31, which = bid >> 10;
    const int t = threadIdx.x, tl = t & 31, th = t >> 5;

    if (which == 0) {
        #pragma unroll
        for (int j = 0; j < 16; ++j) {
            int ar = 2*j + th;
            tile[tl][ar] = Rg[(((size_t)s*32 + q)*32 + ar)*32 + tl];
        }
        __syncthreads();
        _Float16* dst = Rb + ((size_t)s*32 + q)*1024;
        #pragma unroll
        for (int it = 0; it < 4; ++it) {
            int nr = it*8 + (t >> 3), a0 = (t & 7)*4;
            h4 w;
            #pragma unroll
            for (int k = 0; k < 4; ++k) w[k] = (_Float16)tile[nr][a0 + k];
            *(h4*)(dst + nr*32 + a0) = w;
        }
    } else {
        #pragma unroll
        for (int j = 0; j < 16; ++j) {
            int nr = 2*j + th;
            tile[tl][nr] = Og[(((size_t)s*32 + q)*32 + nr)*32 + tl];
        }
        __syncthreads();
        char* dst = Opp + (size_t)s*65536 + q*2048;
        int o = t & 31, cq = t >> 5;
        #pragma unroll
        for (int it = 0; it < 2; ++it) {
            int c = it*2 + cq;
            h8 w;
            #pragma unroll
            for (int k = 0; k < 8; ++k) w[k] = (_Float16)tile[o][c*8 + k];
            *(h8*)(dst + c*512 + o*16) = w;
        }
    }
}

// ---------------- tmake: Tp[s][ks=f*2+gt][o][kk] ----
__global__ __launch_bounds__(256, 2) void tmake_kernel(
    const float* __restrict__ Lg, const _Float16* __restrict__ Rb,
    const char* __restrict__ Opp, char* __restrict__ Tp)
{
    __shared__ __align__(16) char Wl[65536];
    const int bid = blockIdx.x;
    const int s = sdecode(bid & 31), f = bid >> 5;
    const int t = threadIdx.x, wid = t >> 6, l = t & 63;
    const int llo = l & 15, lhi = l >> 4;

    const float* Lsf = Lg + ((size_t)s*32 + f)*1024;
    h8 bfr[2];
    #pragma unroll
    for (int mt = 0; mt < 2; ++mt)
        #pragma unroll
        for (int j = 0; j < 8; ++j)
            bfr[mt][j] = (_Float16)Lsf[(8*lhi + j)*32 + mt*16 + llo];

    const _Float16* Rbs = Rb + (size_t)s*32768;

    #pragma unroll 4
    for (int nt = 0; nt < 16; ++nt) {
        int gnb = (wid*16 + nt)*16;
        h8 af = *(const h8*)(Rbs + (gnb + llo)*32 + 8*lhi);
        int g = gnb >> 5;
        int nbase = (gnb & 31) + 4*lhi;
        #pragma unroll
        for (int mt = 0; mt < 2; ++mt) {
            f32x4 d = __builtin_amdgcn_mfma_f32_16x16x32_f16(af, bfr[mt], (f32x4)(0.f), 0, 0, 0);
            int m = mt*16 + llo;
            h4 w;
            #pragma unroll
            for (int r = 0; r < 4; ++r) w[r] = (_Float16)d[r];
            int byte = (g*2048 + m*64 + nbase*2) ^ ((((g & 7) ^ (m & 7))) << 4);
            *(h4*)(Wl + byte) = w;
        }
    }
    __syncthreads();

    const int ot = wid & 1, kq = wid >> 1;
    const int orow = ot*16 + llo;
    const char* Opps = Opp + (size_t)s*65536;
    f32x4 acc0 = (f32x4)(0.f), acc1 = (f32x4)(0.f);
    #pragma unroll 4
    for (int ksl = 0; ksl < 16; ++ksl) {
        int ks = kq*16 + ksl;
        h8 bf = *(const h8*)(Opps + (ks*4 + lhi)*512 + orow*16);
        {
            int grow = llo;
            int byte = (grow*2048 + ks*64 + lhi*16) ^ ((((grow & 7) ^ (ks & 7))) << 4);
            h8 af = *(const h8*)(Wl + byte);
            acc0 = __builtin_amdgcn_mfma_f32_16x16x32_f16(af, bf, acc0, 0, 0, 0);
        }
        {
            int grow = 16 + llo;
            int byte = (grow*2048 + ks*64 + lhi*16) ^ ((((grow & 7) ^ (ks & 7))) << 4);
            h8 af = *(const h8*)(Wl + byte);
            acc1 = __builtin_amdgcn_mfma_f32_16x16x32_f16(af, bf, acc1, 0, 0, 0);
        }
    }
    __syncthreads();
    if (kq == 1) {
        *(f32x4*)(Wl + ((ot*2 + 0)*64 + l)*16) = acc0;
        *(f32x4*)(Wl + ((ot*2 + 1)*64 + l)*16) = acc1;
    }
    __syncthreads();
    if (kq == 0) {
        acc0 += *(const f32x4*)(Wl + ((ot*2 + 0)*64 + l)*16);
        acc1 += *(const f32x4*)(Wl + ((ot*2 + 1)*64 + l)*16);
        char* Tps = Tp + (size_t)s*65536;
        h4 w0, w1;
        #pragma unroll
        for (int r = 0; r < 4; ++r) { w0[r] = (_Float16)acc0[r]; w1[r] = (_Float16)acc1[r]; }
        *(h4*)(Tps + (f*2 + 0)*1024 + orow*32 + lhi*8) = w0;
        *(h4*)(Tps + (f*2 + 1)*1024 + orow*32 + lhi*8) = w1;
    }
}

// ---------------- main v6: v3 structure + NON-TEMPORAL x loads / out stores
// (x and out streams bypass L2 so the 4-s-per-XCD T working set, 256KB, stays
//  L2-resident; T staging loads remain temporal.)
__global__ __launch_bounds__(256, 2) void main_kernel(
    const float* __restrict__ x, const char* __restrict__ Tp,
    const float* __restrict__ bias, float* __restrict__ out)
{
    __shared__ __align__(16) char Tl[65536];

    const int bid = blockIdx.x;
    const int s = sdecode(bid & 31);
    const int b0 = (bid >> 5) * 128;
    const int t = threadIdx.x, wid = t >> 6, l = t & 63;
    const int lo5 = l & 31, hi = l >> 5;

    const char* Tps = Tp + (size_t)s*65536;
    const float* xrow = x + (size_t)(b0 + wid*32 + lo5)*2048 + s*64;
    const float* bias_s = bias + s*32;

    // ---- issue ALL loads up front: T temporal, x non-temporal ----
    u32x4 tv[16];
    #pragma unroll
    for (int i = 0; i < 16; ++i)
        tv[i] = *(const u32x4*)(Tps + (i*256 + t)*16);

    f32x4 xlv[8];
    #pragma unroll
    for (int i = 0; i < 8; ++i)
        xlv[i] = __builtin_nontemporal_load((const f32x4*)(xrow + i*4));
    const float* xrp = xrow + 32 + hi*8;
    f32x4 xr00 = __builtin_nontemporal_load((const f32x4*)(xrp));
    f32x4 xr01 = __builtin_nontemporal_load((const f32x4*)(xrp + 4));
    f32x4 xr10 = __builtin_nontemporal_load((const f32x4*)(xrp + 16));
    f32x4 xr11 = __builtin_nontemporal_load((const f32x4*)(xrp + 20));

    #pragma unroll
    for (int i = 0; i < 16; ++i)
        *(u32x4*)(Tl + (i*256 + t)*16) = tv[i];

    // convert x to f16 (overlaps in-flight loads)
    h4 xlh[8];
    #pragma unroll
    for (int i = 0; i < 8; ++i) {
        xlh[i][0] = (_Float16)xlv[i][0]; xlh[i][1] = (_Float16)xlv[i][1];
        xlh[i][2] = (_Float16)xlv[i][2]; xlh[i][3] = (_Float16)xlv[i][3];
    }
    h8 xr_a, xr_b;
    xr_a[0] = (_Float16)xr00[0]; xr_a[1] = (_Float16)xr00[1];
    xr_a[2] = (_Float16)xr00[2]; xr_a[3] = (_Float16)xr00[3];
    xr_a[4] = (_Float16)xr01[0]; xr_a[5] = (_Float16)xr01[1];
    xr_a[6] = (_Float16)xr01[2]; xr_a[7] = (_Float16)xr01[3];
    xr_b[0] = (_Float16)xr10[0]; xr_b[1] = (_Float16)xr10[1];
    xr_b[2] = (_Float16)xr10[2]; xr_b[3] = (_Float16)xr10[3];
    xr_b[4] = (_Float16)xr11[0]; xr_b[5] = (_Float16)xr11[1];
    xr_b[6] = (_Float16)xr11[2]; xr_b[7] = (_Float16)xr11[3];
    __syncthreads();

    // ---- K loop: 64 steps, acc ILP=4 ----
    f32x16 acc0 = (f32x16)(0.f), acc1 = (f32x16)(0.f);
    f32x16 acc2 = (f32x16)(0.f), acc3 = (f32x16)(0.f);
    #pragma unroll
    for (int ksl = 0; ksl < 64; ++ksl) {
        h8 bf = *(const h8*)(Tl + ksl*1024 + lo5*32 + hi*16);
        _Float16 xs = xlh[ksl >> 3][(ksl >> 1) & 3];
        if ((ksl & 3) == 0) {
            h8 z = xr_a * xs;
            acc0 = __builtin_amdgcn_mfma_f32_32x32x16_f16(z, bf, acc0, 0, 0, 0);
        } else if ((ksl & 3) == 1) {
            h8 z = xr_b * xs;
            acc1 = __builtin_amdgcn_mfma_f32_32x32x16_f16(z, bf, acc1, 0, 0, 0);
        } else if ((ksl & 3) == 2) {
            h8 z = xr_a * xs;
            acc2 = __builtin_amdgcn_mfma_f32_32x32x16_f16(z, bf, acc2, 0, 0, 0);
        } else {
            h8 z = xr_b * xs;
            acc3 = __builtin_amdgcn_mfma_f32_32x32x16_f16(z, bf, acc3, 0, 0, 0);
        }
    }
    f32x16 acc = (acc0 + acc2) + (acc1 + acc3);

    // ---- epilogue: stash in Tl (dead), non-temporal full-line f32x4 stores ----
    __syncthreads();
    #pragma unroll
    for (int r = 0; r < 16; ++r) {
        int row = (r & 3) + 8*(r >> 2) + 4*hi;          // 32x32 C/D row map
        *(float*)(Tl + wid*4096 + row*128 + lo5*4) = acc[r];
    }
    __syncthreads();

    #pragma unroll
    for (int i = 0; i < 4; ++i) {
        int u = i*256 + t;
        int row = u >> 3, colq = u & 7;
        f32x4 v = *(const f32x4*)(Tl + u*16);
        f32x4 bv = *(const f32x4*)(bias_s + colq*4);
        f32x4 res = v + bv;
        __builtin_nontemporal_store(res,
            (f32x4*)(out + (size_t)(b0 + row)*1024 + s*32 + colq*4));
    }
}

extern "C" void kernel_launch(void* const* d_in, const int* in_sizes, int n_in,
                              void* d_out, int out_size, void* d_ws, size_t ws_size,
                              hipStream_t stream) {
    const float* x    = (const float*)d_in[0];
    const float* L    = (const float*)d_in[1];
    const float* R    = (const float*)d_in[2];
    const float* O    = (const float*)d_in[3];
    const float* bias = (const float*)d_in[4];
    float* out = (float*)d_out;

    _Float16* Rb  = (_Float16*)d_ws;                 // 2 MB
    char*     Opp = (char*)d_ws + 2097152;           // 2 MB
    char*     Tp  = (char*)d_ws + 4194304;           // 2 MB

    conv_kernel<<<dim3(2048), 64, 0, stream>>>(R, O, Rb, Opp);
    tmake_kernel<<<dim3(1024), 256, 0, stream>>>(L, Rb, Opp, Tp);
    main_kernel<<<dim3(512), 256, 0, stream>>>(x, Tp, bias, out);
}

// Round 13
// 30.543 us; speedup vs baseline: 3.3446x; 1.0027x over previous
//
#include <hip/hip_runtime.h>
#include <hip/hip_bf16.h>

// B=2048, NF=64, FD=32, S=32, D=32, OD=32
typedef __attribute__((ext_vector_type(4)))  _Float16 h4;
typedef __attribute__((ext_vector_type(8)))  _Float16 h8;
typedef __attribute__((ext_vector_type(4)))  float f32x4;
typedef __attribute__((ext_vector_type(16))) float f32x16;
typedef __attribute__((ext_vector_type(4)))  unsigned int u32x4;

__device__ __forceinline__ int sdecode(int sp) { return ((sp & 7) << 2) | (sp >> 3); }

// ---------------- conv: Rb[s][g][n][a] f16 ; Opp[s][c8][o][kk] ----
__global__ __launch_bounds__(64) void conv_kernel(
    const float* __restrict__ Rg, const float* __restrict__ Og,
    _Float16* __restrict__ Rb, char* __restrict__ Opp)
{
    __shared__ float tile[32][33];
    const int bid = blockIdx.x;
    const int s = sdecode(bid & 31), q = (bid >> 5) & 31, which = bid >> 10;
    const int t = threadIdx.x, tl = t & 31, th = t >> 5;

    if (which == 0) {
        #pragma unroll
        for (int j = 0; j < 16; ++j) {
            int ar = 2*j + th;
            tile[tl][ar] = Rg[(((size_t)s*32 + q)*32 + ar)*32 + tl];
        }
        __syncthreads();
        _Float16* dst = Rb + ((size_t)s*32 + q)*1024;
        #pragma unroll
        for (int it = 0; it < 4; ++it) {
            int nr = it*8 + (t >> 3), a0 = (t & 7)*4;
            h4 w;
            #pragma unroll
            for (int k = 0; k < 4; ++k) w[k] = (_Float16)tile[nr][a0 + k];
            *(h4*)(dst + nr*32 + a0) = w;
        }
    } else {
        #pragma unroll
        for (int j = 0; j < 16; ++j) {
            int nr = 2*j + th;
            tile[tl][nr] = Og[(((size_t)s*32 + q)*32 + nr)*32 + tl];
        }
        __syncthreads();
        char* dst = Opp + (size_t)s*65536 + q*2048;
        int o = t & 31, cq = t >> 5;
        #pragma unroll
        for (int it = 0; it < 2; ++it) {
            int c = it*2 + cq;
            h8 w;
            #pragma unroll
            for (int k = 0; k < 8; ++k) w[k] = (_Float16)tile[o][c*8 + k];
            *(h8*)(dst + c*512 + o*16) = w;
        }
    }
}

// ---------------- tmake: Tp[s][ks=f*2+gt][o][kk] ----
__global__ __launch_bounds__(256, 2) void tmake_kernel(
    const float* __restrict__ Lg, const _Float16* __restrict__ Rb,
    const char* __restrict__ Opp, char* __restrict__ Tp)
{
    __shared__ __align__(16) char Wl[65536];
    const int bid = blockIdx.x;
    const int s = sdecode(bid & 31), f = bid >> 5;
    const int t = threadIdx.x, wid = t >> 6, l = t & 63;
    const int llo = l & 15, lhi = l >> 4;

    const float* Lsf = Lg + ((size_t)s*32 + f)*1024;
    h8 bfr[2];
    #pragma unroll
    for (int mt = 0; mt < 2; ++mt)
        #pragma unroll
        for (int j = 0; j < 8; ++j)
            bfr[mt][j] = (_Float16)Lsf[(8*lhi + j)*32 + mt*16 + llo];

    const _Float16* Rbs = Rb + (size_t)s*32768;

    #pragma unroll 4
    for (int nt = 0; nt < 16; ++nt) {
        int gnb = (wid*16 + nt)*16;
        h8 af = *(const h8*)(Rbs + (gnb + llo)*32 + 8*lhi);
        int g = gnb >> 5;
        int nbase = (gnb & 31) + 4*lhi;
        #pragma unroll
        for (int mt = 0; mt < 2; ++mt) {
            f32x4 d = __builtin_amdgcn_mfma_f32_16x16x32_f16(af, bfr[mt], (f32x4)(0.f), 0, 0, 0);
            int m = mt*16 + llo;
            h4 w;
            #pragma unroll
            for (int r = 0; r < 4; ++r) w[r] = (_Float16)d[r];
            int byte = (g*2048 + m*64 + nbase*2) ^ ((((g & 7) ^ (m & 7))) << 4);
            *(h4*)(Wl + byte) = w;
        }
    }
    __syncthreads();

    const int ot = wid & 1, kq = wid >> 1;
    const int orow = ot*16 + llo;
    const char* Opps = Opp + (size_t)s*65536;
    f32x4 acc0 = (f32x4)(0.f), acc1 = (f32x4)(0.f);
    #pragma unroll 4
    for (int ksl = 0; ksl < 16; ++ksl) {
        int ks = kq*16 + ksl;
        h8 bf = *(const h8*)(Opps + (ks*4 + lhi)*512 + orow*16);
        {
            int grow = llo;
            int byte = (grow*2048 + ks*64 + lhi*16) ^ ((((grow & 7) ^ (ks & 7))) << 4);
            h8 af = *(const h8*)(Wl + byte);
            acc0 = __builtin_amdgcn_mfma_f32_16x16x32_f16(af, bf, acc0, 0, 0, 0);
        }
        {
            int grow = 16 + llo;
            int byte = (grow*2048 + ks*64 + lhi*16) ^ ((((grow & 7) ^ (ks & 7))) << 4);
            h8 af = *(const h8*)(Wl + byte);
            acc1 = __builtin_amdgcn_mfma_f32_16x16x32_f16(af, bf, acc1, 0, 0, 0);
        }
    }
    __syncthreads();
    if (kq == 1) {
        *(f32x4*)(Wl + ((ot*2 + 0)*64 + l)*16) = acc0;
        *(f32x4*)(Wl + ((ot*2 + 1)*64 + l)*16) = acc1;
    }
    __syncthreads();
    if (kq == 0) {
        acc0 += *(const f32x4*)(Wl + ((ot*2 + 0)*64 + l)*16);
        acc1 += *(const f32x4*)(Wl + ((ot*2 + 1)*64 + l)*16);
        char* Tps = Tp + (size_t)s*65536;
        h4 w0, w1;
        #pragma unroll
        for (int r = 0; r < 4; ++r) { w0[r] = (_Float16)acc0[r]; w1[r] = (_Float16)acc1[r]; }
        *(h4*)(Tps + (f*2 + 0)*1024 + orow*32 + lhi*8) = w0;
        *(h4*)(Tps + (f*2 + 1)*1024 + orow*32 + lhi*8) = w1;
    }
}

// ---------------- main v7: BT=256, 512 threads (8 waves share one T[s] stage)
// grid 256 = (sp = bid&31, btile = bid>>5); 2 blocks/CU, 16 waves/CU.
// T traffic: 256 blocks x 64KB = 16MB (half of v3). One barrier pre-K-loop.
__global__ __launch_bounds__(512, 2) void main_kernel(
    const float* __restrict__ x, const char* __restrict__ Tp,
    const float* __restrict__ bias, float* __restrict__ out)
{
    __shared__ __align__(16) char Tl[65536];

    const int bid = blockIdx.x;
    const int s = sdecode(bid & 31);
    const int b0 = (bid >> 5) * 256;
    const int t = threadIdx.x, wid = t >> 6, l = t & 63;
    const int lo5 = l & 31, hi = l >> 5;

    const char* Tps = Tp + (size_t)s*65536;
    const float* xrow = x + (size_t)(b0 + wid*32 + lo5)*2048 + s*64;
    const float* bias_s = bias + s*32;

    // ---- stage T (8 x 16B per thread) + per-lane x loads, single batch ----
    u32x4 tv[8];
    #pragma unroll
    for (int i = 0; i < 8; ++i)
        tv[i] = *(const u32x4*)(Tps + (i*512 + t)*16);

    float4 xlv[8];
    #pragma unroll
    for (int i = 0; i < 8; ++i) xlv[i] = *(const float4*)(xrow + i*4);
    const float* xrp = xrow + 32 + hi*8;
    float4 xr00 = *(const float4*)(xrp);
    float4 xr01 = *(const float4*)(xrp + 4);
    float4 xr10 = *(const float4*)(xrp + 16);
    float4 xr11 = *(const float4*)(xrp + 20);

    #pragma unroll
    for (int i = 0; i < 8; ++i)
        *(u32x4*)(Tl + (i*512 + t)*16) = tv[i];

    // convert x to f16 (overlaps in-flight loads)
    h4 xlh[8];
    #pragma unroll
    for (int i = 0; i < 8; ++i) {
        xlh[i][0] = (_Float16)xlv[i].x; xlh[i][1] = (_Float16)xlv[i].y;
        xlh[i][2] = (_Float16)xlv[i].z; xlh[i][3] = (_Float16)xlv[i].w;
    }
    h8 xr_a, xr_b;
    xr_a[0] = (_Float16)xr00.x; xr_a[1] = (_Float16)xr00.y;
    xr_a[2] = (_Float16)xr00.z; xr_a[3] = (_Float16)xr00.w;
    xr_a[4] = (_Float16)xr01.x; xr_a[5] = (_Float16)xr01.y;
    xr_a[6] = (_Float16)xr01.z; xr_a[7] = (_Float16)xr01.w;
    xr_b[0] = (_Float16)xr10.x; xr_b[1] = (_Float16)xr10.y;
    xr_b[2] = (_Float16)xr10.z; xr_b[3] = (_Float16)xr10.w;
    xr_b[4] = (_Float16)xr11.x; xr_b[5] = (_Float16)xr11.y;
    xr_b[6] = (_Float16)xr11.z; xr_b[7] = (_Float16)xr11.w;
    __syncthreads();

    // ---- K loop: 64 steps, 1 ds_read_b128 + 1 MFMA, acc ILP=2 ----
    f32x16 acc_e = (f32x16)(0.f), acc_o = (f32x16)(0.f);
    #pragma unroll
    for (int ksl = 0; ksl < 64; ++ksl) {
        h8 bf = *(const h8*)(Tl + ksl*1024 + lo5*32 + hi*16);
        _Float16 xs = xlh[ksl >> 3][(ksl >> 1) & 3];
        if (ksl & 1) {
            h8 z = xr_b * xs;
            acc_o = __builtin_amdgcn_mfma_f32_32x32x16_f16(z, bf, acc_o, 0, 0, 0);
        } else {
            h8 z = xr_a * xs;
            acc_e = __builtin_amdgcn_mfma_f32_32x32x16_f16(z, bf, acc_e, 0, 0, 0);
        }
    }
    f32x16 acc = acc_e + acc_o;

    // ---- epilogue: stash per-wave tiles in Tl (dead), full-line f32x4 stores ----
    __syncthreads();
    #pragma unroll
    for (int r = 0; r < 16; ++r) {
        int row = (r & 3) + 8*(r >> 2) + 4*hi;          // local 0..31
        *(float*)(Tl + wid*4096 + row*128 + lo5*4) = acc[r];
    }
    __syncthreads();

    #pragma unroll
    for (int i = 0; i < 4; ++i) {
        int u = i*512 + t;                 // row = u>>3 (0..255), colq = u&7
        int row = u >> 3, colq = u & 7;
        f32x4 v = *(const f32x4*)(Tl + u*16);
        f32x4 bv = *(const f32x4*)(bias_s + colq*4);
        *(f32x4*)(out + (size_t)(b0 + row)*1024 + s*32 + colq*4) = v + bv;
    }
}

extern "C" void kernel_launch(void* const* d_in, const int* in_sizes, int n_in,
                              void* d_out, int out_size, void* d_ws, size_t ws_size,
                              hipStream_t stream) {
    const float* x    = (const float*)d_in[0];
    const float* L    = (const float*)d_in[1];
    const float* R    = (const float*)d_in[2];
    const float* O    = (const float*)d_in[3];
    const float* bias = (const float*)d_in[4];
    float* out = (float*)d_out;

    _Float16* Rb  = (_Float16*)d_ws;                 // 2 MB
    char*     Opp = (char*)d_ws + 2097152;           // 2 MB
    char*     Tp  = (char*)d_ws + 4194304;           // 2 MB

    conv_kernel<<<dim3(2048), 64, 0, stream>>>(R, O, Rb, Opp);
    tmake_kernel<<<dim3(1024), 256, 0, stream>>>(L, Rb, Opp, Tp);
    main_kernel<<<dim3(256), 512, 0, stream>>>(x, Tp, bias, out);
}